// Round 1
// baseline (1265.967 us; speedup 1.0000x reference)
//
#include <hip/hip_runtime.h>

typedef unsigned short u16;
typedef __bf16 bfrag8 __attribute__((ext_vector_type(8)));
typedef float f32x4 __attribute__((ext_vector_type(4)));

#define MFMA16(a, b, c) __builtin_amdgcn_mfma_f32_16x16x32_bf16((a), (b), (c), 0, 0, 0)

static __device__ __forceinline__ u16 bf_bits(float f) {
  unsigned int u = __builtin_bit_cast(unsigned int, f);
  unsigned int r = (u + 0x7fffu + ((u >> 16) & 1u)) >> 16;
  return (u16)r;
}
static __device__ __forceinline__ float f_from_bits(u16 u) {
  unsigned int w = ((unsigned int)u) << 16;
  return __builtin_bit_cast(float, w);
}

// ---------------- transpose f32 [K][N] -> bf16 [N][K] ----------------
__global__ __launch_bounds__(256) void k_transpose_bf16(const float* __restrict__ src,
                                                        u16* __restrict__ dst,
                                                        int K, int N) {
  __shared__ float tile[32][33];
  const int n0 = blockIdx.x * 32;
  const int k0 = blockIdx.y * 32;
  const int t = threadIdx.x;
  const int lr = t >> 5;   // 0..7
  const int lc = t & 31;
#pragma unroll
  for (int i = 0; i < 4; ++i)
    tile[lr + i * 8][lc] = src[(size_t)(k0 + lr + i * 8) * N + n0 + lc];
  __syncthreads();
#pragma unroll
  for (int i = 0; i < 4; ++i)
    dst[(size_t)(n0 + lr + i * 8) * K + k0 + lc] = bf_bits(tile[lc][lr + i * 8]);
}

// ---------------- rmsnorm: f32 [rows][2048] -> bf16 ----------------
__global__ __launch_bounds__(256) void k_rmsnorm(const float* __restrict__ x,
                                                 const float* __restrict__ sc,
                                                 u16* __restrict__ o) {
  const int row = blockIdx.x;
  const int t = threadIdx.x;
  const float4* x4 = (const float4*)(x + (size_t)row * 2048);
  float4 a = x4[t];
  float4 b = x4[t + 256];
  float ss = a.x * a.x + a.y * a.y + a.z * a.z + a.w * a.w +
             b.x * b.x + b.y * b.y + b.z * b.z + b.w * b.w;
#pragma unroll
  for (int off = 32; off > 0; off >>= 1) ss += __shfl_down(ss, off);
  __shared__ float red[4];
  if ((t & 63) == 0) red[t >> 6] = ss;
  __syncthreads();
  const float inv = rsqrtf((red[0] + red[1] + red[2] + red[3]) * (1.0f / 2048.0f) + 1e-6f);
  const float4* s4 = (const float4*)sc;
  float4 sa = s4[t], sb = s4[t + 256];
  ushort4 pa, pb;
  pa.x = bf_bits(a.x * inv * sa.x); pa.y = bf_bits(a.y * inv * sa.y);
  pa.z = bf_bits(a.z * inv * sa.z); pa.w = bf_bits(a.w * inv * sa.w);
  pb.x = bf_bits(b.x * inv * sb.x); pb.y = bf_bits(b.y * inv * sb.y);
  pb.z = bf_bits(b.z * inv * sb.z); pb.w = bf_bits(b.w * inv * sb.w);
  *(ushort4*)(o + (size_t)row * 2048 + t * 4) = pa;
  *(ushort4*)(o + (size_t)row * 2048 + (t + 256) * 4) = pb;
}

// ---------------- GEMM: A[M][K] bf16 x Bt[N][K] bf16 -> C[M][N] ----------------
// EPI 0: outB = bf16(acc)
// EPI 1: outF = resid + acc          (f32)
// EPI 2: outB = bf16(acc * silu(gate))
template <int EPI>
__global__ __launch_bounds__(256) void k_gemm(const u16* __restrict__ A,
                                              const u16* __restrict__ Bt,
                                              int M, int N, int K,
                                              float* __restrict__ outF,
                                              u16* __restrict__ outB,
                                              const float* __restrict__ resid,
                                              const u16* __restrict__ gate) {
  __shared__ u16 As[128][40];  // +8 pad: 2-way banks only
  __shared__ u16 Bs[128][40];
  const int t = threadIdx.x;
  const int m0 = blockIdx.y * 128;
  const int n0 = blockIdx.x * 128;
  const int wave = t >> 6, lane = t & 63;
  const int wm = wave >> 1, wn = wave & 1;
  const int l15 = lane & 15, lhi = lane >> 4;

  f32x4 acc[4][4];
#pragma unroll
  for (int i = 0; i < 4; ++i)
#pragma unroll
    for (int j = 0; j < 4; ++j) acc[i][j] = (f32x4){0.f, 0.f, 0.f, 0.f};

  const int r0 = t >> 2;          // 0..63
  const int c0 = (t & 3) * 8;     // 0,8,16,24
  const u16* Ap = A + (size_t)(m0 + r0) * K + c0;
  const u16* Bp = Bt + (size_t)(n0 + r0) * K + c0;
  const size_t rowK64 = (size_t)64 * K;

  for (int k0 = 0; k0 < K; k0 += 32) {
    uint4 a0 = *(const uint4*)(Ap + k0);
    uint4 a1 = *(const uint4*)(Ap + rowK64 + k0);
    uint4 b0 = *(const uint4*)(Bp + k0);
    uint4 b1 = *(const uint4*)(Bp + rowK64 + k0);
    __syncthreads();
    *(uint4*)&As[r0][c0] = a0;
    *(uint4*)&As[r0 + 64][c0] = a1;
    *(uint4*)&Bs[r0][c0] = b0;
    *(uint4*)&Bs[r0 + 64][c0] = b1;
    __syncthreads();
    bfrag8 af[4], bq[4];
#pragma unroll
    for (int i = 0; i < 4; ++i) af[i] = *(const bfrag8*)&As[wm * 64 + i * 16 + l15][lhi * 8];
#pragma unroll
    for (int j = 0; j < 4; ++j) bq[j] = *(const bfrag8*)&Bs[wn * 64 + j * 16 + l15][lhi * 8];
#pragma unroll
    for (int i = 0; i < 4; ++i)
#pragma unroll
      for (int j = 0; j < 4; ++j) acc[i][j] = MFMA16(af[i], bq[j], acc[i][j]);
  }

#pragma unroll
  for (int i = 0; i < 4; ++i) {
#pragma unroll
    for (int j = 0; j < 4; ++j) {
      const int mr = m0 + wm * 64 + i * 16 + lhi * 4;
      const int nc = n0 + wn * 64 + j * 16 + l15;
#pragma unroll
      for (int r = 0; r < 4; ++r) {
        const size_t idx = (size_t)(mr + r) * N + nc;
        const float v = acc[i][j][r];
        if (EPI == 0) {
          outB[idx] = bf_bits(v);
        } else if (EPI == 1) {
          outF[idx] = resid[idx] + v;
        } else {
          float g = f_from_bits(gate[idx]);
          float s = g / (1.f + __expf(-g));
          outB[idx] = bf_bits(v * s);
        }
      }
    }
  }
}

// ---------------- causal flash attention ----------------
// qkv: [4096 tokens][6144] bf16 (q|k|v, each head 128 wide). out: [4096][2048] bf16.
__global__ __launch_bounds__(256) void k_attn(const u16* __restrict__ qkv,
                                              u16* __restrict__ out) {
  const int S = 2048, LD = 6144, DH = 128;
  const float scale = 0.0883883476483184405f;  // 1/sqrt(128)
  const int qt = blockIdx.x;  // 0..31 (64-row q tile)
  const int bh = blockIdx.y;  // 0..31
  const int b = bh >> 4, hh = bh & 15;
  const int t = threadIdx.x;
  const int wave = t >> 6, lane = t & 63;
  const int l15 = lane & 15, lhi = lane >> 4;

  __shared__ u16 Vt[128][72];      // V^T tile, key-dim XOR-swizzled per 8-row d block
  __shared__ u16 Pl[4][16][72];    // per-wave P (16 q x 64 key)

  // Q fragments (persist across key tiles)
  const size_t qoff = (size_t)(b * S + qt * 64 + wave * 16 + l15) * LD + hh * DH + lhi * 8;
  bfrag8 qf[4];
#pragma unroll
  for (int ks = 0; ks < 4; ++ks) qf[ks] = *(const bfrag8*)(qkv + qoff + ks * 32);

  f32x4 oacc[8];
#pragma unroll
  for (int j = 0; j < 8; ++j) oacc[j] = (f32x4){0.f, 0.f, 0.f, 0.f};
  float m_i[4], l_i[4];
#pragma unroll
  for (int r = 0; r < 4; ++r) { m_i[r] = -INFINITY; l_i[r] = 0.f; }

  const int q_my = qt * 64 + wave * 16 + lhi * 4;  // + r

  for (int kt = 0; kt <= qt; ++kt) {
    __syncthreads();  // all waves done reading Vt of previous tile
    // stage V tile transposed: coalesced global reads, swizzled LDS writes
#pragma unroll
    for (int c = 0; c < 4; ++c) {
      int ci = t + c * 256;
      int key = ci >> 4;           // 0..63
      int d0 = (ci & 15) * 8;      // 0..120
      const u16* vp = qkv + (size_t)(b * S + kt * 64 + key) * LD + 4096 + hh * DH + d0;
      bfrag8 vv = *(const bfrag8*)vp;
      const u16* pv = (const u16*)&vv;
      int keyS = key ^ (((d0 >> 3) & 7) << 3);
#pragma unroll
      for (int e = 0; e < 8; ++e) Vt[d0 + e][keyS] = pv[e];
    }
    __syncthreads();

    // S = (Q K^T) for 64 keys
    f32x4 sfr[4];
#pragma unroll
    for (int j = 0; j < 4; ++j) {
      sfr[j] = (f32x4){0.f, 0.f, 0.f, 0.f};
#pragma unroll
      for (int ks = 0; ks < 4; ++ks) {
        const u16* kp = qkv + (size_t)(b * S + kt * 64 + j * 16 + l15) * LD + 2048 + hh * DH + ks * 32 + lhi * 8;
        bfrag8 kf = *(const bfrag8*)kp;
        sfr[j] = MFMA16(qf[ks], kf, sfr[j]);
      }
    }
    // scale + causal mask + rowmax
    float sv[4][4], rmax[4];
#pragma unroll
    for (int r = 0; r < 4; ++r) rmax[r] = -INFINITY;
#pragma unroll
    for (int j = 0; j < 4; ++j) {
      int key = kt * 64 + j * 16 + l15;
#pragma unroll
      for (int r = 0; r < 4; ++r) {
        float v = sfr[j][r] * scale;
        v = (key <= q_my + r) ? v : -INFINITY;
        sv[j][r] = v;
        rmax[r] = fmaxf(rmax[r], v);
      }
    }
#pragma unroll
    for (int r = 0; r < 4; ++r) {
      float v = rmax[r];
      v = fmaxf(v, __shfl_xor(v, 1));
      v = fmaxf(v, __shfl_xor(v, 2));
      v = fmaxf(v, __shfl_xor(v, 4));
      v = fmaxf(v, __shfl_xor(v, 8));
      rmax[r] = v;
    }
    float alpha[4], rsum[4];
#pragma unroll
    for (int r = 0; r < 4; ++r) {
      float mn = fmaxf(m_i[r], rmax[r]);
      alpha[r] = __expf(m_i[r] - mn);
      m_i[r] = mn;
      rsum[r] = 0.f;
    }
#pragma unroll
    for (int j = 0; j < 4; ++j) {
#pragma unroll
      for (int r = 0; r < 4; ++r) {
        float p = __expf(sv[j][r] - m_i[r]);
        rsum[r] += p;
        Pl[wave][lhi * 4 + r][j * 16 + l15] = bf_bits(p);
      }
    }
#pragma unroll
    for (int r = 0; r < 4; ++r) {
      float v = rsum[r];
      v += __shfl_xor(v, 1); v += __shfl_xor(v, 2);
      v += __shfl_xor(v, 4); v += __shfl_xor(v, 8);
      l_i[r] = l_i[r] * alpha[r] + v;
    }
#pragma unroll
    for (int j = 0; j < 8; ++j)
#pragma unroll
      for (int r = 0; r < 4; ++r) oacc[j][r] *= alpha[r];

    // O += P @ V   (K=64 in 2 sub-steps)
#pragma unroll
    for (int ks = 0; ks < 2; ++ks) {
      bfrag8 pf = *(const bfrag8*)&Pl[wave][l15][ks * 32 + lhi * 8];
#pragma unroll
      for (int j = 0; j < 8; ++j) {
        int d = j * 16 + l15;
        int key0 = (ks * 32 + lhi * 8) ^ (((d >> 3) & 7) << 3);
        bfrag8 vf = *(const bfrag8*)&Vt[d][key0];
        oacc[j] = MFMA16(pf, vf, oacc[j]);
      }
    }
  }

#pragma unroll
  for (int r = 0; r < 4; ++r) {
    float inv = 1.f / l_i[r];
    size_t row = (size_t)(b * S + qt * 64 + wave * 16 + lhi * 4 + r);
#pragma unroll
    for (int j = 0; j < 8; ++j)
      out[row * 2048 + hh * DH + j * 16 + l15] = bf_bits(oacc[j][r] * inv);
  }
}

// ---------------- launch ----------------
extern "C" void kernel_launch(void* const* d_in, const int* in_sizes, int n_in,
                              void* d_out, int out_size, void* d_ws, size_t ws_size,
                              hipStream_t stream) {
  (void)in_sizes; (void)n_in; (void)out_size; (void)ws_size;
  const float* x      = (const float*)d_in[0];
  const float* w_qkv  = (const float*)d_in[1];
  const float* w_o    = (const float*)d_in[2];
  const float* w_up   = (const float*)d_in[3];
  const float* w_gate = (const float*)d_in[4];
  const float* w_down = (const float*)d_in[5];
  const float* scale1 = (const float*)d_in[6];
  const float* scale2 = (const float*)d_in[7];
  float* out = (float*)d_out;

  // workspace layout (bf16 elements unless noted); total 251.7 MB
  u16* B       = (u16*)d_ws;
  u16* wqkvT   = B;                               // [6144][2048]
  u16* woT     = wqkvT  + (size_t)6144 * 2048;    // [2048][2048]
  u16* wgateT  = woT    + (size_t)2048 * 2048;    // [8192][2048]
  u16* wupT    = wgateT + (size_t)8192 * 2048;    // [8192][2048]
  u16* wdownT  = wupT   + (size_t)8192 * 2048;    // [2048][8192]
  u16* xn      = wdownT + (size_t)2048 * 8192;    // [4096][2048]
  u16* qkvb    = xn     + (size_t)4096 * 2048;    // [4096][6144]
  u16* attnb   = qkvb   + (size_t)4096 * 6144;    // [4096][2048]
  float* y1    = (float*)(attnb + (size_t)4096 * 2048);  // [4096][2048] f32
  u16* gbuf    = qkvb;    // alias: qkv+attn dead after out-proj (exactly 4096*8192)
  u16* hbuf    = wqkvT;   // alias: wqkvT+woT+wgateT dead after gate GEMM (exactly 4096*8192)

  dim3 blk(256);
  k_transpose_bf16<<<dim3(192, 64), blk, 0, stream>>>(w_qkv,  wqkvT,  2048, 6144);
  k_transpose_bf16<<<dim3(64, 64),  blk, 0, stream>>>(w_o,    woT,    2048, 2048);
  k_transpose_bf16<<<dim3(256, 64), blk, 0, stream>>>(w_gate, wgateT, 2048, 8192);
  k_transpose_bf16<<<dim3(256, 64), blk, 0, stream>>>(w_up,   wupT,   2048, 8192);
  k_transpose_bf16<<<dim3(64, 256), blk, 0, stream>>>(w_down, wdownT, 8192, 2048);

  k_rmsnorm<<<4096, blk, 0, stream>>>(x, scale1, xn);
  k_gemm<0><<<dim3(48, 32), blk, 0, stream>>>(xn, wqkvT, 4096, 6144, 2048, nullptr, qkvb, nullptr, nullptr);
  k_attn<<<dim3(32, 32), blk, 0, stream>>>(qkvb, attnb);
  k_gemm<1><<<dim3(16, 32), blk, 0, stream>>>(attnb, woT, 4096, 2048, 2048, y1, nullptr, x, nullptr);
  k_rmsnorm<<<4096, blk, 0, stream>>>(y1, scale2, xn);
  k_gemm<0><<<dim3(64, 32), blk, 0, stream>>>(xn, wgateT, 4096, 8192, 2048, nullptr, gbuf, nullptr, nullptr);
  k_gemm<2><<<dim3(64, 32), blk, 0, stream>>>(xn, wupT, 4096, 8192, 2048, nullptr, hbuf, nullptr, gbuf);
  k_gemm<1><<<dim3(16, 32), blk, 0, stream>>>(hbuf, wdownT, 4096, 2048, 8192, out, nullptr, y1, nullptr);
}

// Round 2
// 1081.601 us; speedup vs baseline: 1.1705x; 1.1705x over previous
//
#include <hip/hip_runtime.h>

typedef unsigned short u16;
typedef __bf16 bfrag8 __attribute__((ext_vector_type(8)));
typedef float f32x4 __attribute__((ext_vector_type(4)));

#define MFMA16(a, b, c) __builtin_amdgcn_mfma_f32_16x16x32_bf16((a), (b), (c), 0, 0, 0)

static __device__ __forceinline__ u16 bf_bits(float f) {
  unsigned int u = __builtin_bit_cast(unsigned int, f);
  unsigned int r = (u + 0x7fffu + ((u >> 16) & 1u)) >> 16;
  return (u16)r;
}
static __device__ __forceinline__ float f_from_bits(u16 u) {
  unsigned int w = ((unsigned int)u) << 16;
  return __builtin_bit_cast(float, w);
}
static __device__ __forceinline__ void gload16(const void* g, void* l) {
  __builtin_amdgcn_global_load_lds(
      (const __attribute__((address_space(1))) void*)g,
      (__attribute__((address_space(3))) void*)l, 16, 0, 0);
}

// ---------------- transpose f32 [K][N] -> bf16 [N][K] ----------------
__global__ __launch_bounds__(256) void k_transpose_bf16(const float* __restrict__ src,
                                                        u16* __restrict__ dst,
                                                        int K, int N) {
  __shared__ float tile[32][33];
  const int n0 = blockIdx.x * 32;
  const int k0 = blockIdx.y * 32;
  const int t = threadIdx.x;
  const int lr = t >> 5;
  const int lc = t & 31;
#pragma unroll
  for (int i = 0; i < 4; ++i)
    tile[lr + i * 8][lc] = src[(size_t)(k0 + lr + i * 8) * N + n0 + lc];
  __syncthreads();
#pragma unroll
  for (int i = 0; i < 4; ++i)
    dst[(size_t)(n0 + lr + i * 8) * K + k0 + lc] = bf_bits(tile[lc][lr + i * 8]);
}

// ---------------- transpose V out of qkv: -> vtg[bh][128 d][2048 tok] ----------------
__global__ __launch_bounds__(256) void k_transpose_v(const u16* __restrict__ qkv,
                                                     u16* __restrict__ vtg) {
  __shared__ u16 tile[32][33];
  const int bh = blockIdx.z, b = bh >> 4, hh = bh & 15;
  const int s0 = blockIdx.x * 32, d0 = blockIdx.y * 32;
  const int t = threadIdx.x;
  const int lr = t >> 5, lc = t & 31;
#pragma unroll
  for (int i = 0; i < 4; ++i)
    tile[lr + i * 8][lc] =
        qkv[(size_t)(b * 2048 + s0 + lr + i * 8) * 6144 + 4096 + hh * 128 + d0 + lc];
  __syncthreads();
#pragma unroll
  for (int i = 0; i < 4; ++i)
    vtg[(size_t)bh * 128 * 2048 + (size_t)(d0 + lr + i * 8) * 2048 + s0 + lc] =
        tile[lc][lr + i * 8];
}

// ---------------- rmsnorm: f32 [rows][2048] -> bf16 ----------------
__global__ __launch_bounds__(256) void k_rmsnorm(const float* __restrict__ x,
                                                 const float* __restrict__ sc,
                                                 u16* __restrict__ o) {
  const int row = blockIdx.x;
  const int t = threadIdx.x;
  const float4* x4 = (const float4*)(x + (size_t)row * 2048);
  float4 a = x4[t];
  float4 b = x4[t + 256];
  float ss = a.x * a.x + a.y * a.y + a.z * a.z + a.w * a.w +
             b.x * b.x + b.y * b.y + b.z * b.z + b.w * b.w;
#pragma unroll
  for (int off = 32; off > 0; off >>= 1) ss += __shfl_down(ss, off);
  __shared__ float red[4];
  if ((t & 63) == 0) red[t >> 6] = ss;
  __syncthreads();
  const float inv = rsqrtf((red[0] + red[1] + red[2] + red[3]) * (1.0f / 2048.0f) + 1e-6f);
  const float4* s4 = (const float4*)sc;
  float4 sa = s4[t], sb = s4[t + 256];
  ushort4 pa, pb;
  pa.x = bf_bits(a.x * inv * sa.x); pa.y = bf_bits(a.y * inv * sa.y);
  pa.z = bf_bits(a.z * inv * sa.z); pa.w = bf_bits(a.w * inv * sa.w);
  pb.x = bf_bits(b.x * inv * sb.x); pb.y = bf_bits(b.y * inv * sb.y);
  pb.z = bf_bits(b.z * inv * sb.z); pb.w = bf_bits(b.w * inv * sb.w);
  *(ushort4*)(o + (size_t)row * 2048 + t * 4) = pa;
  *(ushort4*)(o + (size_t)row * 2048 + (t + 256) * 4) = pb;
}

// ---------------- GEMM (m97 structure): A[M][K] x Bt[N][K] -> C[M][N] ----------------
template <int EPI>
__global__ __launch_bounds__(256) void k_gemm(const u16* __restrict__ A,
                                              const u16* __restrict__ Bt,
                                              int M, int N, int K,
                                              float* __restrict__ outF,
                                              u16* __restrict__ outB,
                                              const float* __restrict__ resid,
                                              const u16* __restrict__ gate) {
  __shared__ u16 As[128][32];   // linear: global_load_lds dest
  __shared__ u16 Bs[128][32];
  const int t = threadIdx.x;
  const int m0 = blockIdx.y * 128;
  const int n0 = blockIdx.x * 128;
  const int wave = t >> 6, lane = t & 63;
  const int wm = wave >> 1, wn = wave & 1;
  const int l15 = lane & 15, lhi = lane >> 4;

  f32x4 acc[4][4];
#pragma unroll
  for (int i = 0; i < 4; ++i)
#pragma unroll
    for (int j = 0; j < 4; ++j) acc[i][j] = (f32x4){0.f, 0.f, 0.f, 0.f};

  const int r0 = t >> 2;          // 0..63
  const int c0 = (t & 3) * 8;     // 0,8,16,24
  const u16* Ap0 = A + (size_t)(m0 + r0) * K + c0;
  const u16* Ap1 = A + (size_t)(m0 + 64 + r0) * K + c0;
  const u16* Bp0 = Bt + (size_t)(n0 + r0) * K + c0;
  const u16* Bp1 = Bt + (size_t)(n0 + 64 + r0) * K + c0;
  char* AsB = (char*)&As[0][0];
  char* BsB = (char*)&Bs[0][0];
  const unsigned int ldso0 = wave * 1024 + lane * 16;
  const unsigned int ldso1 = 4096 + wave * 1024 + lane * 16;

  for (int k0 = 0; k0 < K; k0 += 32) {
    __syncthreads();
    gload16(Ap0 + k0, AsB + ldso0);
    gload16(Ap1 + k0, AsB + ldso1);
    gload16(Bp0 + k0, BsB + ldso0);
    gload16(Bp1 + k0, BsB + ldso1);
    __syncthreads();
    bfrag8 af[4], bq[4];
#pragma unroll
    for (int i = 0; i < 4; ++i) af[i] = *(const bfrag8*)&As[wm * 64 + i * 16 + l15][lhi * 8];
#pragma unroll
    for (int j = 0; j < 4; ++j) bq[j] = *(const bfrag8*)&Bs[wn * 64 + j * 16 + l15][lhi * 8];
#pragma unroll
    for (int i = 0; i < 4; ++i)
#pragma unroll
      for (int j = 0; j < 4; ++j) acc[i][j] = MFMA16(af[i], bq[j], acc[i][j]);
  }

#pragma unroll
  for (int i = 0; i < 4; ++i) {
#pragma unroll
    for (int j = 0; j < 4; ++j) {
      const int mr = m0 + wm * 64 + i * 16 + lhi * 4;
      const int nc = n0 + wn * 64 + j * 16 + l15;
#pragma unroll
      for (int r = 0; r < 4; ++r) {
        const size_t idx = (size_t)(mr + r) * N + nc;
        const float v = acc[i][j][r];
        if (EPI == 0) {
          outB[idx] = bf_bits(v);
        } else if (EPI == 1) {
          outF[idx] = resid[idx] + v;
        } else {
          float g = f_from_bits(gate[idx]);
          float s = g / (1.f + __expf(-g));
          outB[idx] = bf_bits(v * s);
        }
      }
    }
  }
}

// ---------------- causal flash attention (8 waves, QBLK=128, KVBLK=64) ----------------
__global__ __launch_bounds__(512) void k_attn(const u16* __restrict__ qkv,
                                              const u16* __restrict__ vtg,
                                              u16* __restrict__ out) {
  const int S = 2048, LD = 6144;
  const float scale = 0.0883883476483184405f;  // 1/sqrt(128)
  const int bh = blockIdx.y;
  const int b = bh >> 4, hh = bh & 15;
  // pairwise load balance: co-resident pairs (y, y+16) get qt and 15-qt
  const int qt = (b == 0) ? (15 - (int)blockIdx.x) : (int)blockIdx.x;
  const int t = threadIdx.x;
  const int wave = t >> 6, lane = t & 63;
  const int l15 = lane & 15, lhi = lane >> 4;
  const int lhi16 = lhi * 16;
  const int swz = (l15 & 7) << 4;   // byte-XOR for fragment reads

  __shared__ u16 Kt[64 * 128];      // [key][128 d], 256B rows, byte^=((key&7)<<4)
  __shared__ u16 Vt[128 * 64];      // [d][64 key], 128B rows, byte^=((d&7)<<4)
  __shared__ u16 Pl[8][16][72];
  char* KtC = (char*)Kt;
  char* VtC = (char*)Vt;

  // persistent Q fragments
  const int qrow = qt * 128 + wave * 16 + l15;
  const size_t qoff = (size_t)(b * S + qrow) * LD + hh * 128 + lhi * 8;
  bfrag8 qf[4];
#pragma unroll
  for (int ks = 0; ks < 4; ++ks) qf[ks] = *(const bfrag8*)(qkv + qoff + ks * 32);

  f32x4 oacc[8];
#pragma unroll
  for (int j = 0; j < 8; ++j) oacc[j] = (f32x4){0.f, 0.f, 0.f, 0.f};
  float m_i[4], l_i[4];
#pragma unroll
  for (int r = 0; r < 4; ++r) { m_i[r] = -INFINITY; l_i[r] = 0.f; }

  const int q_my = qt * 128 + wave * 16 + lhi * 4;
  const int q_wave_last = qt * 128 + wave * 16 + 15;

  // staging sources (pre-swizzled global addresses; LDS dest stays linear)
  const int keyA = t >> 4, keyB = 32 + (t >> 4);
  const int oK = (t & 15) * 16;                 // byte-in-row (256B rows)
  const int dA = t >> 3, dB = 64 + (t >> 3);
  const int oV = (t & 7) * 16;                  // byte-in-row (128B rows)
  const u16* kbase = qkv + (size_t)(b * S) * LD + 2048 + hh * 128;
  const u16* vbase = vtg + (size_t)bh * 128 * S;
  const u16* ksrcA = kbase + (size_t)keyA * LD + ((oK ^ ((keyA & 7) << 4)) >> 1);
  const u16* ksrcB = kbase + (size_t)keyB * LD + ((oK ^ ((keyB & 7) << 4)) >> 1);
  const u16* vsrcA = vbase + (size_t)dA * S + ((oV ^ ((dA & 7) << 4)) >> 1);
  const u16* vsrcB = vbase + (size_t)dB * S + ((oV ^ ((dB & 7) << 4)) >> 1);
  const unsigned int ldso0 = wave * 1024 + lane * 16;
  const unsigned int ldso1 = 8192 + wave * 1024 + lane * 16;
  const size_t kstep = (size_t)64 * LD;

  const int kt_max = 2 * qt + 1;
  for (int kt = 0; kt <= kt_max; ++kt) {
    __syncthreads();
    gload16(ksrcA + (size_t)kt * kstep, KtC + ldso0);
    gload16(ksrcB + (size_t)kt * kstep, KtC + ldso1);
    gload16(vsrcA + kt * 64, VtC + ldso0);
    gload16(vsrcB + kt * 64, VtC + ldso1);
    __syncthreads();

    if (kt * 64 <= q_wave_last) {
      // ---- S = Q K^T ----
      f32x4 sfr[4];
#pragma unroll
      for (int j = 0; j < 4; ++j) {
        sfr[j] = (f32x4){0.f, 0.f, 0.f, 0.f};
        const int krow = j * 16 + l15;
#pragma unroll
        for (int ks = 0; ks < 4; ++ks) {
          bfrag8 kf = *(const bfrag8*)(KtC + krow * 256 + ((ks * 64 + lhi16) ^ swz));
          sfr[j] = MFMA16(qf[ks], kf, sfr[j]);
        }
      }
      // ---- mask + online softmax ----
      float sv[4][4], rmax[4];
#pragma unroll
      for (int r = 0; r < 4; ++r) rmax[r] = -INFINITY;
#pragma unroll
      for (int j = 0; j < 4; ++j) {
        const int key = kt * 64 + j * 16 + l15;
#pragma unroll
        for (int r = 0; r < 4; ++r) {
          float v = sfr[j][r] * scale;
          v = (key <= q_my + r) ? v : -INFINITY;
          sv[j][r] = v;
          rmax[r] = fmaxf(rmax[r], v);
        }
      }
#pragma unroll
      for (int r = 0; r < 4; ++r) {
        float v = rmax[r];
        v = fmaxf(v, __shfl_xor(v, 1));
        v = fmaxf(v, __shfl_xor(v, 2));
        v = fmaxf(v, __shfl_xor(v, 4));
        v = fmaxf(v, __shfl_xor(v, 8));
        rmax[r] = v;
      }
      float alpha[4], rsum[4];
#pragma unroll
      for (int r = 0; r < 4; ++r) {
        float mn = fmaxf(m_i[r], rmax[r]);
        alpha[r] = __expf(m_i[r] - mn);
        m_i[r] = mn;
        rsum[r] = 0.f;
      }
#pragma unroll
      for (int j = 0; j < 4; ++j) {
#pragma unroll
        for (int r = 0; r < 4; ++r) {
          float p = __expf(sv[j][r] - m_i[r]);
          rsum[r] += p;
          Pl[wave][lhi * 4 + r][j * 16 + l15] = bf_bits(p);
        }
      }
#pragma unroll
      for (int r = 0; r < 4; ++r) {
        float v = rsum[r];
        v += __shfl_xor(v, 1); v += __shfl_xor(v, 2);
        v += __shfl_xor(v, 4); v += __shfl_xor(v, 8);
        l_i[r] = l_i[r] * alpha[r] + v;
      }
#pragma unroll
      for (int j = 0; j < 8; ++j)
#pragma unroll
        for (int r = 0; r < 4; ++r) oacc[j][r] *= alpha[r];

      // ---- O += P @ V ----
#pragma unroll
      for (int ks2 = 0; ks2 < 2; ++ks2) {
        bfrag8 pf = *(const bfrag8*)&Pl[wave][l15][ks2 * 32 + lhi * 8];
#pragma unroll
        for (int j = 0; j < 8; ++j) {
          const int d = j * 16 + l15;
          bfrag8 vf = *(const bfrag8*)(VtC + d * 128 + ((ks2 * 64 + lhi16) ^ swz));
          oacc[j] = MFMA16(pf, vf, oacc[j]);
        }
      }
    }
  }

#pragma unroll
  for (int r = 0; r < 4; ++r) {
    const float inv = 1.f / l_i[r];
    const size_t tok = (size_t)b * S + qt * 128 + wave * 16 + lhi * 4 + r;
#pragma unroll
    for (int j = 0; j < 8; ++j)
      out[tok * 2048 + hh * 128 + j * 16 + l15] = bf_bits(oacc[j][r] * inv);
  }
}

// ---------------- launch ----------------
extern "C" void kernel_launch(void* const* d_in, const int* in_sizes, int n_in,
                              void* d_out, int out_size, void* d_ws, size_t ws_size,
                              hipStream_t stream) {
  (void)in_sizes; (void)n_in; (void)out_size; (void)ws_size;
  const float* x      = (const float*)d_in[0];
  const float* w_qkv  = (const float*)d_in[1];
  const float* w_o    = (const float*)d_in[2];
  const float* w_up   = (const float*)d_in[3];
  const float* w_gate = (const float*)d_in[4];
  const float* w_down = (const float*)d_in[5];
  const float* scale1 = (const float*)d_in[6];
  const float* scale2 = (const float*)d_in[7];
  float* out = (float*)d_out;

  u16* B       = (u16*)d_ws;
  u16* wqkvT   = B;                               // [6144][2048]
  u16* woT     = wqkvT  + (size_t)6144 * 2048;    // [2048][2048]
  u16* wgateT  = woT    + (size_t)2048 * 2048;    // [8192][2048]
  u16* wupT    = wgateT + (size_t)8192 * 2048;    // [8192][2048]
  u16* wdownT  = wupT   + (size_t)8192 * 2048;    // [2048][8192]
  u16* xn      = wdownT + (size_t)2048 * 8192;    // [4096][2048]
  u16* qkvb    = xn     + (size_t)4096 * 2048;    // [4096][6144]
  u16* attnb   = qkvb   + (size_t)4096 * 6144;    // [4096][2048]
  float* y1    = (float*)(attnb + (size_t)4096 * 2048);  // [4096][2048] f32
  u16* vtg     = (u16*)y1;   // alias: vtg (16.8MB) dead before y1 is written
  u16* gbuf    = qkvb;       // alias: qkv+attn dead after out-proj
  u16* hbuf    = wqkvT;      // alias: wqkvT+woT+wgateT dead after gate GEMM

  dim3 blk(256);
  k_transpose_bf16<<<dim3(192, 64), blk, 0, stream>>>(w_qkv,  wqkvT,  2048, 6144);
  k_transpose_bf16<<<dim3(64, 64),  blk, 0, stream>>>(w_o,    woT,    2048, 2048);
  k_transpose_bf16<<<dim3(256, 64), blk, 0, stream>>>(w_gate, wgateT, 2048, 8192);
  k_transpose_bf16<<<dim3(256, 64), blk, 0, stream>>>(w_up,   wupT,   2048, 8192);
  k_transpose_bf16<<<dim3(64, 256), blk, 0, stream>>>(w_down, wdownT, 8192, 2048);

  k_rmsnorm<<<4096, blk, 0, stream>>>(x, scale1, xn);
  k_gemm<0><<<dim3(48, 32), blk, 0, stream>>>(xn, wqkvT, 4096, 6144, 2048, nullptr, qkvb, nullptr, nullptr);
  k_transpose_v<<<dim3(64, 4, 32), blk, 0, stream>>>(qkvb, vtg);
  k_attn<<<dim3(16, 32), dim3(512), 0, stream>>>(qkvb, vtg, attnb);
  k_gemm<1><<<dim3(16, 32), blk, 0, stream>>>(attnb, woT, 4096, 2048, 2048, y1, nullptr, x, nullptr);
  k_rmsnorm<<<4096, blk, 0, stream>>>(y1, scale2, xn);
  k_gemm<0><<<dim3(64, 32), blk, 0, stream>>>(xn, wgateT, 4096, 8192, 2048, nullptr, gbuf, nullptr, nullptr);
  k_gemm<2><<<dim3(64, 32), blk, 0, stream>>>(xn, wupT, 4096, 8192, 2048, nullptr, hbuf, nullptr, gbuf);
  k_gemm<1><<<dim3(16, 32), blk, 0, stream>>>(hbuf, wdownT, 4096, 2048, 8192, out, nullptr, y1, nullptr);
}

// Round 4
// 908.586 us; speedup vs baseline: 1.3933x; 1.1904x over previous
//
#include <hip/hip_runtime.h>

typedef unsigned short u16;
typedef __bf16 bfrag8 __attribute__((ext_vector_type(8)));
typedef float f32x4 __attribute__((ext_vector_type(4)));

#define MFMA16(a, b, c) __builtin_amdgcn_mfma_f32_16x16x32_bf16((a), (b), (c), 0, 0, 0)

static __device__ __forceinline__ u16 bf_bits(float f) {
  unsigned int u = __builtin_bit_cast(unsigned int, f);
  unsigned int r = (u + 0x7fffu + ((u >> 16) & 1u)) >> 16;
  return (u16)r;
}
static __device__ __forceinline__ float f_from_bits(u16 u) {
  unsigned int w = ((unsigned int)u) << 16;
  return __builtin_bit_cast(float, w);
}
static __device__ __forceinline__ void gload16(const void* g, void* l) {
  __builtin_amdgcn_global_load_lds(
      (const __attribute__((address_space(1))) void*)g,
      (__attribute__((address_space(3))) void*)l, 16, 0, 0);
}

// ---------------- transpose f32 [K][N] -> bf16 [N][K] ----------------
__global__ __launch_bounds__(256) void k_transpose_bf16(const float* __restrict__ src,
                                                        u16* __restrict__ dst,
                                                        int K, int N) {
  __shared__ float tile[32][33];
  const int n0 = blockIdx.x * 32;
  const int k0 = blockIdx.y * 32;
  const int t = threadIdx.x;
  const int lr = t >> 5;
  const int lc = t & 31;
#pragma unroll
  for (int i = 0; i < 4; ++i)
    tile[lr + i * 8][lc] = src[(size_t)(k0 + lr + i * 8) * N + n0 + lc];
  __syncthreads();
#pragma unroll
  for (int i = 0; i < 4; ++i)
    dst[(size_t)(n0 + lr + i * 8) * K + k0 + lc] = bf_bits(tile[lc][lr + i * 8]);
}

// ---------------- transpose V out of qkv: -> vtg[bh][128 d][2048 tok] ----------------
__global__ __launch_bounds__(256) void k_transpose_v(const u16* __restrict__ qkv,
                                                     u16* __restrict__ vtg) {
  __shared__ u16 tile[32][33];
  const int bh = blockIdx.z, b = bh >> 4, hh = bh & 15;
  const int s0 = blockIdx.x * 32, d0 = blockIdx.y * 32;
  const int t = threadIdx.x;
  const int lr = t >> 5, lc = t & 31;
#pragma unroll
  for (int i = 0; i < 4; ++i)
    tile[lr + i * 8][lc] =
        qkv[(size_t)(b * 2048 + s0 + lr + i * 8) * 6144 + 4096 + hh * 128 + d0 + lc];
  __syncthreads();
#pragma unroll
  for (int i = 0; i < 4; ++i)
    vtg[(size_t)bh * 128 * 2048 + (size_t)(d0 + lr + i * 8) * 2048 + s0 + lc] =
        tile[lc][lr + i * 8];
}

// ---------------- rmsnorm: f32 [rows][2048] -> bf16 ----------------
__global__ __launch_bounds__(256) void k_rmsnorm(const float* __restrict__ x,
                                                 const float* __restrict__ sc,
                                                 u16* __restrict__ o) {
  const int row = blockIdx.x;
  const int t = threadIdx.x;
  const float4* x4 = (const float4*)(x + (size_t)row * 2048);
  float4 a = x4[t];
  float4 b = x4[t + 256];
  float ss = a.x * a.x + a.y * a.y + a.z * a.z + a.w * a.w +
             b.x * b.x + b.y * b.y + b.z * b.z + b.w * b.w;
#pragma unroll
  for (int off = 32; off > 0; off >>= 1) ss += __shfl_down(ss, off);
  __shared__ float red[4];
  if ((t & 63) == 0) red[t >> 6] = ss;
  __syncthreads();
  const float inv = rsqrtf((red[0] + red[1] + red[2] + red[3]) * (1.0f / 2048.0f) + 1e-6f);
  const float4* s4 = (const float4*)sc;
  float4 sa = s4[t], sb = s4[t + 256];
  ushort4 pa, pb;
  pa.x = bf_bits(a.x * inv * sa.x); pa.y = bf_bits(a.y * inv * sa.y);
  pa.z = bf_bits(a.z * inv * sa.z); pa.w = bf_bits(a.w * inv * sa.w);
  pb.x = bf_bits(b.x * inv * sb.x); pb.y = bf_bits(b.y * inv * sb.y);
  pb.z = bf_bits(b.z * inv * sb.z); pb.w = bf_bits(b.w * inv * sb.w);
  *(ushort4*)(o + (size_t)row * 2048 + t * 4) = pa;
  *(ushort4*)(o + (size_t)row * 2048 + (t + 256) * 4) = pb;
}

// ---------------- 256x256 8-phase GEMM: A[M][K] x Bt[N][K] -> C[M][N] ----------------
// 8 waves (2M x 4N), BK=64, LDS 128KB double-buffered, XOR-swizzled, counted vmcnt.
// LDS A region H (16KB): vrow v in [0,128) <-> global row m0 + (v>>6)*128 + H*64 + (v&63),
// 128B rows, byte-in-row XOR ((vrow&7)<<4) (via pre-swizzled global src, m173).
// STAGE: one gload16 per 1024B wave-chunk at base + lane*16 (m104 wave-uniform rule);
// wave w, load0 -> vrows w*16+[0,8), load1 -> vrows w*16+8+[0,8); lane: row=w*16+(lane>>3),
// bytecol=(lane&7)*16.
#define LDA(SB, H, MF, KH)                                                       \
  (*(const bfrag8*)(smC + (SB) * 65536 + (H) * 16384 +                           \
                    (wm * 64 + (MF) * 16 + l15) * 128 + (((KH) * 64 + lhi16) ^ swz)))
#define LDB(SB, NF, KH)                                                          \
  (*(const bfrag8*)(smC + (SB) * 65536 + 32768 +                                 \
                    (wn * 64 + (NF) * 16 + l15) * 128 + (((KH) * 64 + lhi16) ^ swz)))
#define STAGE_A(SB, H, KT)                                                       \
  {                                                                              \
    const u16* s_ = Asrc + (size_t)(H) * AhK + (size_t)(KT) * 64;                \
    char* d_ = smC + (SB) * 65536 + (H) * 16384 + wchunk;                        \
    gload16(s_, d_);                                                             \
    gload16(s_ + K8, d_ + 1024);                                                 \
  }
#define STAGE_B(SB, C, KT)                                                       \
  {                                                                              \
    const u16* s_ = Bsrc + (size_t)(C) * BcK + (size_t)(KT) * 64;                \
    char* d_ = smC + (SB) * 65536 + 32768 + (C) * 16384 + wchunk;                \
    gload16(s_, d_);                                                             \
    gload16(s_ + K8, d_ + 1024);                                                 \
  }
#define MM(H, I, J, AF, BF) acc[(H) * 4 + (I)][J] = MFMA16(AF, BF, acc[(H) * 4 + (I)][J])
#define PHASE(SB, H, KH, STAGE_STMT, TAIL_VM)                                    \
  {                                                                              \
    bfrag8 a0_ = LDA(SB, H, 0, KH), a1_ = LDA(SB, H, 1, KH),                     \
           a2_ = LDA(SB, H, 2, KH), a3_ = LDA(SB, H, 3, KH);                     \
    bfrag8 b0_ = LDB(SB, 0, KH), b1_ = LDB(SB, 1, KH),                           \
           b2_ = LDB(SB, 2, KH), b3_ = LDB(SB, 3, KH);                           \
    STAGE_STMT;                                                                  \
    __builtin_amdgcn_s_barrier();                                                \
    asm volatile("s_waitcnt lgkmcnt(0)" ::: "memory");                           \
    __builtin_amdgcn_sched_barrier(0);                                           \
    __builtin_amdgcn_s_setprio(1);                                               \
    MM(H, 0, 0, a0_, b0_); MM(H, 0, 1, a0_, b1_);                                \
    MM(H, 0, 2, a0_, b2_); MM(H, 0, 3, a0_, b3_);                                \
    MM(H, 1, 0, a1_, b0_); MM(H, 1, 1, a1_, b1_);                                \
    MM(H, 1, 2, a1_, b2_); MM(H, 1, 3, a1_, b3_);                                \
    MM(H, 2, 0, a2_, b0_); MM(H, 2, 1, a2_, b1_);                                \
    MM(H, 2, 2, a2_, b2_); MM(H, 2, 3, a2_, b3_);                                \
    MM(H, 3, 0, a3_, b0_); MM(H, 3, 1, a3_, b1_);                                \
    MM(H, 3, 2, a3_, b2_); MM(H, 3, 3, a3_, b3_);                                \
    __builtin_amdgcn_s_setprio(0);                                               \
    TAIL_VM;                                                                     \
    __builtin_amdgcn_s_barrier();                                                \
    asm volatile("" ::: "memory");                                               \
    __builtin_amdgcn_sched_barrier(0);                                           \
  }
#define VM2                                                                      \
  {                                                                              \
    asm volatile("s_waitcnt vmcnt(2)" ::: "memory");                             \
    __builtin_amdgcn_sched_barrier(0);                                           \
  }
#define NOPVM (void)0

template <int EPI>
__global__ __launch_bounds__(512, 1) void k_gemm8(const u16* __restrict__ A,
                                                  const u16* __restrict__ Bt,
                                                  int M, int N, int K,
                                                  float* __restrict__ outF,
                                                  u16* __restrict__ outB,
                                                  const float* __restrict__ resid,
                                                  const u16* __restrict__ gate) {
  __shared__ u16 sm[2 * 32768];  // 128 KiB: [slot][A 32KB | B 32KB]
  char* smC = (char*)sm;
  const int t = threadIdx.x;
  const int m0 = blockIdx.y * 256;
  const int n0 = blockIdx.x * 256;
  const int wid = t >> 6, lane = t & 63;
  const int wm = wid >> 2, wn = wid & 3;
  const int l15 = lane & 15, lhi = lane >> 4;
  const int lhi16 = lhi * 16;
  const int swz = (l15 & 7) << 4;

  f32x4 acc[8][4];
#pragma unroll
  for (int i = 0; i < 8; ++i)
#pragma unroll
    for (int j = 0; j < 4; ++j) acc[i][j] = (f32x4){0.f, 0.f, 0.f, 0.f};

  // staging per-thread constants (wave-chunk layout, m104-compliant)
  const int sr = lane >> 3;                      // sub-row 0..7
  const int csw = ((lane & 7) * 16 ^ (sr << 4)) >> 1;  // pre-swizzled u16 col
  const u16* Asrc = A + (size_t)(m0 + (wid >> 2) * 128 + (wid & 3) * 16 + sr) * K + csw;
  const u16* Bsrc = Bt + (size_t)(n0 + wid * 16 + sr) * K + csw;
  const unsigned wchunk = (unsigned)wid * 2048 + (unsigned)lane * 16;
  const size_t K8 = (size_t)8 * K;
  const size_t AhK = (size_t)64 * K;
  const size_t BcK = (size_t)128 * K;

  const int NT = K >> 6;  // K-tiles (even: K in {2048, 8192})

  // prologue: tile0 -> slot0 (4 regions), tile1.A0 -> slot1
  STAGE_A(0, 0, 0);
  STAGE_B(0, 0, 0);
  STAGE_B(0, 1, 0);
  STAGE_A(0, 1, 0);
  STAGE_A(1, 0, 1);
  VM2;  // tile0's 8 loads landed; s1.A0 may be in flight
  __builtin_amdgcn_s_barrier();
  asm volatile("" ::: "memory");
  __builtin_amdgcn_sched_barrier(0);

  for (int it = 0; it < (NT >> 1); ++it) {
    const int kt1 = 2 * it + 1;
    const int kt2 = (2 * it + 2 < NT) ? 2 * it + 2 : NT - 1;
    const int kt3 = (2 * it + 3 < NT) ? 2 * it + 3 : NT - 1;
    PHASE(0, 0, 0, STAGE_A(1, 1, kt1), NOPVM);
    PHASE(0, 1, 0, STAGE_B(1, 0, kt1), NOPVM);
    PHASE(0, 0, 1, STAGE_B(1, 1, kt1), NOPVM);
    PHASE(0, 1, 1, STAGE_A(0, 0, kt2), VM2);
    PHASE(1, 0, 0, STAGE_B(0, 0, kt2), NOPVM);
    PHASE(1, 1, 0, STAGE_B(0, 1, kt2), NOPVM);
    PHASE(1, 0, 1, STAGE_A(0, 1, kt2), NOPVM);
    PHASE(1, 1, 1, STAGE_A(1, 0, kt3), VM2);
  }

  // epilogue
#pragma unroll
  for (int mf = 0; mf < 8; ++mf) {
#pragma unroll
    for (int nf = 0; nf < 4; ++nf) {
      const int mr = m0 + wm * 128 + mf * 16 + lhi * 4;
      const int nc = n0 + wn * 64 + nf * 16 + l15;
#pragma unroll
      for (int r = 0; r < 4; ++r) {
        const size_t idx = (size_t)(mr + r) * N + nc;
        const float v = acc[mf][nf][r];
        if (EPI == 0) {
          outB[idx] = bf_bits(v);
        } else if (EPI == 1) {
          outF[idx] = resid[idx] + v;
        } else {
          float g = f_from_bits(gate[idx]);
          float s = g / (1.f + __expf(-g));
          outB[idx] = bf_bits(v * s);
        }
      }
    }
  }
}

// ---------------- causal flash attention (8 waves, QBLK=128, KVBLK=64) ----------------
__global__ __launch_bounds__(512) void k_attn(const u16* __restrict__ qkv,
                                              const u16* __restrict__ vtg,
                                              u16* __restrict__ out) {
  const int S = 2048, LD = 6144;
  const float scale = 0.0883883476483184405f;  // 1/sqrt(128)
  const int bh = blockIdx.y;
  const int b = bh >> 4, hh = bh & 15;
  const int qt = (b == 0) ? (15 - (int)blockIdx.x) : (int)blockIdx.x;
  const int t = threadIdx.x;
  const int wave = t >> 6, lane = t & 63;
  const int l15 = lane & 15, lhi = lane >> 4;
  const int lhi16 = lhi * 16;
  const int swz = (l15 & 7) << 4;

  __shared__ u16 Kt[64 * 128];
  __shared__ u16 Vt[128 * 64];
  __shared__ u16 Pl[8][16][72];
  char* KtC = (char*)Kt;
  char* VtC = (char*)Vt;

  const int qrow = qt * 128 + wave * 16 + l15;
  const size_t qoff = (size_t)(b * S + qrow) * LD + hh * 128 + lhi * 8;
  bfrag8 qf[4];
#pragma unroll
  for (int ks = 0; ks < 4; ++ks) qf[ks] = *(const bfrag8*)(qkv + qoff + ks * 32);

  f32x4 oacc[8];
#pragma unroll
  for (int j = 0; j < 8; ++j) oacc[j] = (f32x4){0.f, 0.f, 0.f, 0.f};
  float m_i[4], l_i[4];
#pragma unroll
  for (int r = 0; r < 4; ++r) { m_i[r] = -INFINITY; l_i[r] = 0.f; }

  const int q_my = qt * 128 + wave * 16 + lhi * 4;
  const int q_wave_last = qt * 128 + wave * 16 + 15;

  const int keyA = t >> 4, keyB = 32 + (t >> 4);
  const int oK = (t & 15) * 16;
  const int dA = t >> 3, dB = 64 + (t >> 3);
  const int oV = (t & 7) * 16;
  const u16* kbase = qkv + (size_t)(b * S) * LD + 2048 + hh * 128;
  const u16* vbase = vtg + (size_t)bh * 128 * S;
  const u16* ksrcA = kbase + (size_t)keyA * LD + ((oK ^ ((keyA & 7) << 4)) >> 1);
  const u16* ksrcB = kbase + (size_t)keyB * LD + ((oK ^ ((keyB & 7) << 4)) >> 1);
  const u16* vsrcA = vbase + (size_t)dA * S + ((oV ^ ((dA & 7) << 4)) >> 1);
  const u16* vsrcB = vbase + (size_t)dB * S + ((oV ^ ((dB & 7) << 4)) >> 1);
  const unsigned int ldso0 = wave * 1024 + lane * 16;
  const unsigned int ldso1 = 8192 + wave * 1024 + lane * 16;
  const size_t kstep = (size_t)64 * LD;

  const int kt_max = 2 * qt + 1;
  for (int kt = 0; kt <= kt_max; ++kt) {
    __syncthreads();
    gload16(ksrcA + (size_t)kt * kstep, KtC + ldso0);
    gload16(ksrcB + (size_t)kt * kstep, KtC + ldso1);
    gload16(vsrcA + kt * 64, VtC + ldso0);
    gload16(vsrcB + kt * 64, VtC + ldso1);
    __syncthreads();

    if (kt * 64 <= q_wave_last) {
      f32x4 sfr[4];
#pragma unroll
      for (int j = 0; j < 4; ++j) {
        sfr[j] = (f32x4){0.f, 0.f, 0.f, 0.f};
        const int krow = j * 16 + l15;
#pragma unroll
        for (int ks = 0; ks < 4; ++ks) {
          bfrag8 kf = *(const bfrag8*)(KtC + krow * 256 + ((ks * 64 + lhi16) ^ swz));
          sfr[j] = MFMA16(qf[ks], kf, sfr[j]);
        }
      }
      float sv[4][4], rmax[4];
#pragma unroll
      for (int r = 0; r < 4; ++r) rmax[r] = -INFINITY;
#pragma unroll
      for (int j = 0; j < 4; ++j) {
        const int key = kt * 64 + j * 16 + l15;
#pragma unroll
        for (int r = 0; r < 4; ++r) {
          float v = sfr[j][r] * scale;
          v = (key <= q_my + r) ? v : -INFINITY;
          sv[j][r] = v;
          rmax[r] = fmaxf(rmax[r], v);
        }
      }
#pragma unroll
      for (int r = 0; r < 4; ++r) {
        float v = rmax[r];
        v = fmaxf(v, __shfl_xor(v, 1));
        v = fmaxf(v, __shfl_xor(v, 2));
        v = fmaxf(v, __shfl_xor(v, 4));
        v = fmaxf(v, __shfl_xor(v, 8));
        rmax[r] = v;
      }
      float alpha[4], rsum[4];
#pragma unroll
      for (int r = 0; r < 4; ++r) {
        float mn = fmaxf(m_i[r], rmax[r]);
        alpha[r] = __expf(m_i[r] - mn);
        m_i[r] = mn;
        rsum[r] = 0.f;
      }
#pragma unroll
      for (int j = 0; j < 4; ++j) {
#pragma unroll
        for (int r = 0; r < 4; ++r) {
          float p = __expf(sv[j][r] - m_i[r]);
          rsum[r] += p;
          Pl[wave][lhi * 4 + r][j * 16 + l15] = bf_bits(p);
        }
      }
#pragma unroll
      for (int r = 0; r < 4; ++r) {
        float v = rsum[r];
        v += __shfl_xor(v, 1); v += __shfl_xor(v, 2);
        v += __shfl_xor(v, 4); v += __shfl_xor(v, 8);
        l_i[r] = l_i[r] * alpha[r] + v;
      }
#pragma unroll
      for (int j = 0; j < 8; ++j)
#pragma unroll
        for (int r = 0; r < 4; ++r) oacc[j][r] *= alpha[r];

#pragma unroll
      for (int ks2 = 0; ks2 < 2; ++ks2) {
        bfrag8 pf = *(const bfrag8*)&Pl[wave][l15][ks2 * 32 + lhi * 8];
#pragma unroll
        for (int j = 0; j < 8; ++j) {
          const int d = j * 16 + l15;
          bfrag8 vf = *(const bfrag8*)(VtC + d * 128 + ((ks2 * 64 + lhi16) ^ swz));
          oacc[j] = MFMA16(pf, vf, oacc[j]);
        }
      }
    }
  }

#pragma unroll
  for (int r = 0; r < 4; ++r) {
    const float inv = 1.f / l_i[r];
    const size_t tok = (size_t)b * S + qt * 128 + wave * 16 + lhi * 4 + r;
#pragma unroll
    for (int j = 0; j < 8; ++j)
      out[tok * 2048 + hh * 128 + j * 16 + l15] = bf_bits(oacc[j][r] * inv);
  }
}

// ---------------- launch ----------------
extern "C" void kernel_launch(void* const* d_in, const int* in_sizes, int n_in,
                              void* d_out, int out_size, void* d_ws, size_t ws_size,
                              hipStream_t stream) {
  (void)in_sizes; (void)n_in; (void)out_size; (void)ws_size;
  const float* x      = (const float*)d_in[0];
  const float* w_qkv  = (const float*)d_in[1];
  const float* w_o    = (const float*)d_in[2];
  const float* w_up   = (const float*)d_in[3];
  const float* w_gate = (const float*)d_in[4];
  const float* w_down = (const float*)d_in[5];
  const float* scale1 = (const float*)d_in[6];
  const float* scale2 = (const float*)d_in[7];
  float* out = (float*)d_out;

  u16* B       = (u16*)d_ws;
  u16* wqkvT   = B;                               // [6144][2048]
  u16* woT     = wqkvT  + (size_t)6144 * 2048;    // [2048][2048]
  u16* wgateT  = woT    + (size_t)2048 * 2048;    // [8192][2048]
  u16* wupT    = wgateT + (size_t)8192 * 2048;    // [8192][2048]
  u16* wdownT  = wupT   + (size_t)8192 * 2048;    // [2048][8192]
  u16* xn      = wdownT + (size_t)2048 * 8192;    // [4096][2048]
  u16* qkvb    = xn     + (size_t)4096 * 2048;    // [4096][6144]
  u16* attnb   = qkvb   + (size_t)4096 * 6144;    // [4096][2048]
  float* y1    = (float*)(attnb + (size_t)4096 * 2048);  // [4096][2048] f32
  u16* vtg     = (u16*)y1;   // alias: vtg dead before y1 written
  u16* gbuf    = qkvb;       // alias: qkv+attn dead after out-proj
  u16* hbuf    = wqkvT;      // alias: wqkvT+woT+wgateT dead after gate GEMM

  dim3 blk(256);
  k_transpose_bf16<<<dim3(192, 64), blk, 0, stream>>>(w_qkv,  wqkvT,  2048, 6144);
  k_transpose_bf16<<<dim3(64, 64),  blk, 0, stream>>>(w_o,    woT,    2048, 2048);
  k_transpose_bf16<<<dim3(256, 64), blk, 0, stream>>>(w_gate, wgateT, 2048, 8192);
  k_transpose_bf16<<<dim3(256, 64), blk, 0, stream>>>(w_up,   wupT,   2048, 8192);
  k_transpose_bf16<<<dim3(64, 256), blk, 0, stream>>>(w_down, wdownT, 8192, 2048);

  k_rmsnorm<<<4096, blk, 0, stream>>>(x, scale1, xn);
  k_gemm8<0><<<dim3(24, 16), dim3(512), 0, stream>>>(xn, wqkvT, 4096, 6144, 2048, nullptr, qkvb, nullptr, nullptr);
  k_transpose_v<<<dim3(64, 4, 32), blk, 0, stream>>>(qkvb, vtg);
  k_attn<<<dim3(16, 32), dim3(512), 0, stream>>>(qkvb, vtg, attnb);
  k_gemm8<1><<<dim3(8, 16), dim3(512), 0, stream>>>(attnb, woT, 4096, 2048, 2048, y1, nullptr, x, nullptr);
  k_rmsnorm<<<4096, blk, 0, stream>>>(y1, scale2, xn);
  k_gemm8<0><<<dim3(32, 16), dim3(512), 0, stream>>>(xn, wgateT, 4096, 8192, 2048, nullptr, gbuf, nullptr, nullptr);
  k_gemm8<2><<<dim3(32, 16), dim3(512), 0, stream>>>(xn, wupT, 4096, 8192, 2048, nullptr, hbuf, nullptr, gbuf);
  k_gemm8<1><<<dim3(8, 16), dim3(512), 0, stream>>>(hbuf, wdownT, 4096, 2048, 8192, out, nullptr, y1, nullptr);
}